// Round 2
// baseline (605.455 us; speedup 1.0000x reference)
//
#include <hip/hip_runtime.h>
#include <hip/hip_bf16.h>

// Problem: B=32, S=2048, ENC=1024, DEC=512
//   h_proj[b,e]   = sum_d hidden[b,d] * W[e,d]            (Wh = W[:, :512])
//   e_proj[b,s,d] = sum_e enc[b,s,e] * W[d, 512+e]        (We = W[:, 512:])
//   energy = tanh(e_proj + h_proj + bias); scores = v . energy; attn = softmax_s

typedef __attribute__((ext_vector_type(8))) short bf16x8;
typedef __attribute__((ext_vector_type(4))) float f32x4;

__device__ __forceinline__ ushort f2bf(float x) {
    __hip_bfloat16 h = __float2bfloat16(x);
    return *reinterpret_cast<ushort*>(&h);
}

__device__ __forceinline__ bf16x8 pack8(float4 a, float4 b) {
    bf16x8 o;
    o[0] = (short)f2bf(a.x); o[1] = (short)f2bf(a.y);
    o[2] = (short)f2bf(a.z); o[3] = (short)f2bf(a.w);
    o[4] = (short)f2bf(b.x); o[5] = (short)f2bf(b.y);
    o[6] = (short)f2bf(b.z); o[7] = (short)f2bf(b.w);
    return o;
}

// ws layout (bytes):
//   [0, 1MB)            : Wbf  bf16 [512][1024]  (We: row n=d, col k=e, k-contiguous)
//   [1MB, 1MB+64KB)     : hb   f32  [32][512]    (h_proj + bias)
//   [1MB+64KB, +256KB)  : scores f32 [32][2048]
#define WS_WBF   0
#define WS_HB    (1u << 20)
#define WS_SCORE ((1u << 20) + (64u << 10))

// ---- We -> bf16, layout [d][e] ----
__global__ void convert_we(const float* __restrict__ W, ushort* __restrict__ Wbf) {
    int idx = blockIdx.x * 256 + threadIdx.x;
    int d  = idx >> 8;
    int e4 = (idx & 255) * 4;
    float4 f = *(const float4*)(W + (size_t)d * 1536 + 512 + e4);
    ushort4 u;
    u.x = f2bf(f.x); u.y = f2bf(f.y); u.z = f2bf(f.z); u.w = f2bf(f.w);
    *(ushort4*)(Wbf + (size_t)d * 1024 + e4) = u;
}

// ---- hb[b][d] = hidden[b] . W[d][0:512] + bias[d]  (exact fp32) ----
__global__ void hproj_kernel(const float* __restrict__ hidden,
                             const float* __restrict__ W,
                             const float* __restrict__ bias,
                             float* __restrict__ hb) {
    int idx = blockIdx.x * 256 + threadIdx.x;   // 16384 = 32*512
    int b = idx >> 9, d = idx & 511;
    const float4* hp = (const float4*)(hidden + b * 512);
    const float4* wp = (const float4*)(W + (size_t)d * 1536);
    float acc = 0.f;
#pragma unroll 8
    for (int j = 0; j < 128; ++j) {
        float4 h = hp[j], w = wp[j];
        acc += h.x * w.x + h.y * w.y + h.z * w.z + h.w * w.w;
    }
    hb[idx] = acc + bias[d];
}

// ---- main: e_proj GEMM (M=65536,N=512,K=1024) fused tanh + v-dot -> scores ----
// 2048 blocks x 256 thr (4 waves). Block: 32 M-rows x all 512 N-cols, BK=64.
// A staged raw fp32 via async global_load_lds into double-buffered LDS
// (XOR-swizzled at 16B granularity via the global->lane mapping); f32->bf16 at
// fragment build. Per kt: all B-frags preloaded to regs BEFORE the barrier so
// no vmcnt wait occurs mid-compute (vmcnt is FIFO); next tile's staging issued
// right after the barrier and flies during compute.
__launch_bounds__(256, 3)
__global__ void eproj_scores(const float* __restrict__ enc,
                             const ushort* __restrict__ Wbf,
                             const float* __restrict__ hb,
                             const float* __restrict__ v,
                             float* __restrict__ scores) {
    __shared__ float Abuf[2][32 * 64];   // 2 x 8KB fp32, 16B-swizzled
    __shared__ float spart[4][32];

    const int tid  = threadIdx.x;
    const int lane = tid & 63, w = tid >> 6;
    const int q    = lane >> 4, ln = lane & 15;
    const long m0  = (long)blockIdx.x * 32;
    const int bidx = (int)(m0 >> 11);     // batch row (no straddle: 64 blocks per b)
    const int nbase = w * 128;

    f32x4 acc[2][8];
#pragma unroll
    for (int mt = 0; mt < 2; ++mt)
#pragma unroll
        for (int nt = 0; nt < 8; ++nt)
            acc[mt][nt] = (f32x4){0.f, 0.f, 0.f, 0.f};

    // pre-stage tile kt=0 into Abuf[0]
#pragma unroll
    for (int rr = 0; rr < 2; ++rr) {
        int p = rr * 256 + tid;            // 16B-slot index 0..511
        int r = p >> 4;
        int c = (p & 15) ^ (r & 15);       // XOR swizzle
        const float* g = enc + (m0 + r) * 1024 + c * 4;
        float* lb = &Abuf[0][(rr * 256 + w * 64) * 4];   // wave-uniform base
        __builtin_amdgcn_global_load_lds(
            (const __attribute__((address_space(1))) void*)g,
            (__attribute__((address_space(3))) void*)lb, 16, 0, 0);
    }

    int buf = 0;
    for (int kt = 0; kt < 1024; kt += 64) {
        // preload ALL B fragments for this kt (L2-hot; issued before barrier)
        bf16x8 bfr[2][8];
#pragma unroll
        for (int ks2 = 0; ks2 < 2; ++ks2)
#pragma unroll
            for (int nt = 0; nt < 8; ++nt)
                bfr[ks2][nt] = *(const bf16x8*)(
                    Wbf + (size_t)(nbase + nt * 16 + ln) * 1024 + kt + ks2 * 32 + q * 8);

        __syncthreads();   // drains prev staging + B-preloads; Abuf[buf] ready

        // issue async staging of next tile into the other buffer
        if (kt + 64 < 1024) {
#pragma unroll
            for (int rr = 0; rr < 2; ++rr) {
                int p = rr * 256 + tid;
                int r = p >> 4;
                int c = (p & 15) ^ (r & 15);
                const float* g = enc + (m0 + r) * 1024 + (kt + 64) + c * 4;
                float* lb = &Abuf[buf ^ 1][(rr * 256 + w * 64) * 4];
                __builtin_amdgcn_global_load_lds(
                    (const __attribute__((address_space(1))) void*)g,
                    (__attribute__((address_space(3))) void*)lb, 16, 0, 0);
            }
        }

        // compute from regs (B) + LDS (A): no vmcnt waits in here
        const float* lcur = Abuf[buf];
#pragma unroll
        for (int ks2 = 0; ks2 < 2; ++ks2) {
            bf16x8 af[2];
#pragma unroll
            for (int mt = 0; mt < 2; ++mt) {
                int r  = ln + 16 * mt;
                int cb = ks2 * 8 + 2 * q;              // 16B-chunk of first half
                int pA = r * 16 + ( cb      ^ (r & 15));
                int pB = r * 16 + ((cb + 1) ^ (r & 15));
                float4 a0 = *(const float4*)(lcur + pA * 4);
                float4 a1 = *(const float4*)(lcur + pB * 4);
                af[mt] = pack8(a0, a1);
            }
#pragma unroll
            for (int nt = 0; nt < 8; ++nt)
#pragma unroll
                for (int mt = 0; mt < 2; ++mt)
                    acc[mt][nt] = __builtin_amdgcn_mfma_f32_16x16x32_bf16(
                        af[mt], bfr[ks2][nt], acc[mt][nt], 0, 0, 0);
        }
        buf ^= 1;
    }

    // epilogue: energy = tanh(acc + hb), partial = sum_d v[d]*energy
    float partial[2][4];
#pragma unroll
    for (int mt = 0; mt < 2; ++mt)
#pragma unroll
        for (int r = 0; r < 4; ++r) partial[mt][r] = 0.f;

#pragma unroll
    for (int nt = 0; nt < 8; ++nt) {
        int d = nbase + nt * 16 + ln;
        float hbv = hb[bidx * 512 + d];
        float vv  = v[d];
#pragma unroll
        for (int mt = 0; mt < 2; ++mt)
#pragma unroll
            for (int r = 0; r < 4; ++r) {
                float x = acc[mt][nt][r] + hbv;
                float e = __expf(2.f * x);          // tanh(x) = 1 - 2/(e^{2x}+1)
                partial[mt][r] += vv * (1.f - 2.f / (e + 1.f));
            }
    }
    // reduce across the 16 lanes of each quad-row group
#pragma unroll
    for (int mt = 0; mt < 2; ++mt)
#pragma unroll
        for (int r = 0; r < 4; ++r) {
            float s = partial[mt][r];
            s += __shfl_xor(s, 1);
            s += __shfl_xor(s, 2);
            s += __shfl_xor(s, 4);
            s += __shfl_xor(s, 8);
            partial[mt][r] = s;
        }
    if (ln == 0) {
#pragma unroll
        for (int mt = 0; mt < 2; ++mt)
#pragma unroll
            for (int r = 0; r < 4; ++r)
                spart[w][mt * 16 + q * 4 + r] = partial[mt][r];
    }
    __syncthreads();
    if (tid < 32) {
        float s = spart[0][tid] + spart[1][tid] + spart[2][tid] + spart[3][tid];
        scores[m0 + tid] = s;
    }
}

// ---- softmax over S=2048 per b ----
__global__ void softmax_kernel(const float* __restrict__ scores, float* __restrict__ out) {
    int b = blockIdx.x;
    const float* sc = scores + b * 2048;
    __shared__ float wred[4], wsum[4];

    float lmax = -1e30f;
    for (int i = threadIdx.x; i < 2048; i += 256) lmax = fmaxf(lmax, sc[i]);
#pragma unroll
    for (int m = 1; m < 64; m <<= 1) lmax = fmaxf(lmax, __shfl_xor(lmax, m));
    if ((threadIdx.x & 63) == 0) wred[threadIdx.x >> 6] = lmax;
    __syncthreads();
    float gmax = fmaxf(fmaxf(wred[0], wred[1]), fmaxf(wred[2], wred[3]));

    float lsum = 0.f;
    for (int i = threadIdx.x; i < 2048; i += 256) lsum += __expf(sc[i] - gmax);
#pragma unroll
    for (int m = 1; m < 64; m <<= 1) lsum += __shfl_xor(lsum, m);
    if ((threadIdx.x & 63) == 0) wsum[threadIdx.x >> 6] = lsum;
    __syncthreads();
    float inv = 1.f / (wsum[0] + wsum[1] + wsum[2] + wsum[3]);

    for (int i = threadIdx.x; i < 2048; i += 256)
        out[b * 2048 + i] = __expf(sc[i] - gmax) * inv;
}

extern "C" void kernel_launch(void* const* d_in, const int* in_sizes, int n_in,
                              void* d_out, int out_size, void* d_ws, size_t ws_size,
                              hipStream_t stream) {
    const float* hidden = (const float*)d_in[0];   // 32 x 512
    const float* enc    = (const float*)d_in[1];   // 32 x 2048 x 1024
    const float* W      = (const float*)d_in[2];   // 512 x 1536
    const float* bias   = (const float*)d_in[3];   // 512
    const float* v      = (const float*)d_in[4];   // 512
    float* out = (float*)d_out;                    // 32 x 1 x 2048

    char* ws = (char*)d_ws;
    ushort* Wbf   = (ushort*)(ws + WS_WBF);
    float*  hb    = (float*)(ws + WS_HB);
    float*  score = (float*)(ws + WS_SCORE);

    hipLaunchKernelGGL(convert_we,   dim3(512),  dim3(256), 0, stream, W, Wbf);
    hipLaunchKernelGGL(hproj_kernel, dim3(64),   dim3(256), 0, stream, hidden, W, bias, hb);
    hipLaunchKernelGGL(eproj_scores, dim3(2048), dim3(256), 0, stream, enc, Wbf, hb, v, score);
    hipLaunchKernelGGL(softmax_kernel, dim3(32), dim3(256), 0, stream, score, out);
}

// Round 3
// 508.525 us; speedup vs baseline: 1.1906x; 1.1906x over previous
//
#include <hip/hip_runtime.h>
#include <hip/hip_bf16.h>

// Problem: B=32, S=2048, ENC=1024, DEC=512
//   h_proj[b,e]   = sum_d hidden[b,d] * W[e,d]            (Wh = W[:, :512])
//   e_proj[b,s,d] = sum_e enc[b,s,e] * W[d, 512+e]        (We = W[:, 512:])
//   energy = tanh(e_proj + h_proj + bias); scores = v . energy; attn = softmax_s

typedef __attribute__((ext_vector_type(8))) short bf16x8;
typedef __attribute__((ext_vector_type(4))) float f32x4;

__device__ __forceinline__ ushort f2bf(float x) {
    __hip_bfloat16 h = __float2bfloat16(x);
    return *reinterpret_cast<ushort*>(&h);
}

__device__ __forceinline__ bf16x8 pack8(float4 a, float4 b) {
    bf16x8 o;
    o[0] = (short)f2bf(a.x); o[1] = (short)f2bf(a.y);
    o[2] = (short)f2bf(a.z); o[3] = (short)f2bf(a.w);
    o[4] = (short)f2bf(b.x); o[5] = (short)f2bf(b.y);
    o[6] = (short)f2bf(b.z); o[7] = (short)f2bf(b.w);
    return o;
}

// ws layout (bytes):
//   [0, 1MB)            : Wbf  bf16 [512][1024]  (We: row n=d, col k=e, k-contiguous)
//   [1MB, 1MB+64KB)     : hb   f32  [32][512]    (h_proj + bias)
//   [1MB+64KB, +256KB)  : scores f32 [32][2048]  (zeroed by prep; eproj atomicAdds)
#define WS_WBF   0
#define WS_HB    (1u << 20)
#define WS_SCORE ((1u << 20) + (64u << 10))

// ---- prep: convert We->bf16 (blocks 0..511), hproj (512..575), zero scores (576..639)
__global__ void prep_kernel(const float* __restrict__ W,
                            const float* __restrict__ hidden,
                            const float* __restrict__ bias,
                            ushort* __restrict__ Wbf,
                            float* __restrict__ hb,
                            float* __restrict__ score) {
    const int bid = blockIdx.x, tid = threadIdx.x;
    if (bid < 512) {
        int idx = bid * 256 + tid;
        int d  = idx >> 8;
        int e4 = (idx & 255) * 4;
        float4 f = *(const float4*)(W + (size_t)d * 1536 + 512 + e4);
        ushort4 u;
        u.x = f2bf(f.x); u.y = f2bf(f.y); u.z = f2bf(f.z); u.w = f2bf(f.w);
        *(ushort4*)(Wbf + (size_t)d * 1024 + e4) = u;
    } else if (bid < 576) {
        int idx = (bid - 512) * 256 + tid;        // 0..16383 = 32*512
        int b = idx >> 9, d = idx & 511;
        const float4* hp = (const float4*)(hidden + b * 512);
        const float4* wp = (const float4*)(W + (size_t)d * 1536);
        float acc = 0.f;
#pragma unroll 8
        for (int j = 0; j < 128; ++j) {
            float4 h = hp[j], w = wp[j];
            acc += h.x * w.x + h.y * w.y + h.z * w.z + h.w * w.w;
        }
        hb[idx] = acc + bias[d];
    } else {
        int idx = (bid - 576) * 256 + tid;        // 16384 threads x 4 floats = 65536
        float4 z = {0.f, 0.f, 0.f, 0.f};
        *(float4*)(score + (size_t)idx * 4) = z;
    }
}

// ---- main: e_proj GEMM (M=65536,N=512,K=1024) fused tanh + v-dot -> scores ----
// Grid 2048 = 512 M-blocks x 4 N-blocks (N fast => A-tile L3 temporal locality).
// Block 256 thr, 2x2 waves, wave tile 64x64 (acc 4x4 f32x4 = 64 regs), BK=32.
// A: f32 via async global_load_lds, double-buffered, XOR-swizzled 16B slots
//    (frag ds_read_b128 lands <=2-way on banks = free).
// B: 4 bf16x8 frags in regs, prefetched for kt+1 AFTER the A-DMA issue and held
//    across the barrier. Compute phase has NO vmem-dependent reads (lgkm only);
//    the barrier's vmcnt(0) drain only covers loads issued a full compute ago.
__launch_bounds__(256, 3)
__global__ void eproj_scores(const float* __restrict__ enc,
                             const ushort* __restrict__ Wbf,
                             const float* __restrict__ hb,
                             const float* __restrict__ v,
                             float* __restrict__ scores) {
    __shared__ alignas(16) float Abuf[2][128 * 32];   // 2 x 16KB, swizzled 16B slots
    __shared__ float spart[2][128];

    const int tid  = threadIdx.x;
    const int lane = tid & 63, w = tid >> 6;
    const int wm = w >> 1, wn = w & 1;
    const int q = lane >> 4, ln = lane & 15;
    const int  nblk = blockIdx.x & 3;
    const long m0   = (long)(blockIdx.x >> 2) * 128;
    const int  bidx = (int)(m0 >> 11);        // 16 M-blocks per batch row, no straddle
    const int  n0   = nblk * 128 + wn * 64;

    f32x4 acc[4][4];
#pragma unroll
    for (int mt = 0; mt < 4; ++mt)
#pragma unroll
        for (int nt = 0; nt < 4; ++nt)
            acc[mt][nt] = (f32x4){0.f, 0.f, 0.f, 0.f};

    // B row pointers (per nt), k advances by 32 bf16 = 64B per kt
    const ushort* bptr[4];
#pragma unroll
    for (int nt = 0; nt < 4; ++nt)
        bptr[nt] = Wbf + (size_t)(n0 + nt * 16 + ln) * 1024 + q * 8;

    // A-frag swizzled slot offsets (in floats), invariant over kt
    int sA0[4], sA1[4];
#pragma unroll
    for (int mt = 0; mt < 4; ++mt) {
        int rA = wm * 64 + mt * 16 + ln;
        sA0[mt] = (rA * 8 + ((2 * q)     ^ (rA & 7))) * 4;
        sA1[mt] = (rA * 8 + ((2 * q + 1) ^ (rA & 7))) * 4;
    }

    // initial: stage A tile kt=0 into Abuf[0] (async), preload B frags kt=0
#pragma unroll
    for (int i = 0; i < 4; ++i) {
        int s = i * 256 + tid;                 // 16B-slot id 0..1023
        int r = s >> 3;
        int c = (s & 7) ^ (r & 7);             // XOR swizzle
        const float* g = enc + (m0 + r) * 1024 + c * 4;
        float* lb = &Abuf[0][(i * 256 + w * 64) * 4];   // wave-uniform base
        __builtin_amdgcn_global_load_lds(
            (const __attribute__((address_space(1))) void*)g,
            (__attribute__((address_space(3))) void*)lb, 16, 0, 0);
    }
    bf16x8 bfr[2][4];
#pragma unroll
    for (int nt = 0; nt < 4; ++nt)
        bfr[0][nt] = *(const bf16x8*)(bptr[nt]);

    int buf = 0;
#pragma unroll 2
    for (int kt = 0; kt < 32; ++kt) {
        const int p = kt & 1;
        __syncthreads();   // drains: A-DMA of tile kt + B prefetch (both had a full compute phase)

        if (kt < 31) {
            // issue A-DMA for tile kt+1 into the other buffer (flies during compute)
#pragma unroll
            for (int i = 0; i < 4; ++i) {
                int s = i * 256 + tid;
                int r = s >> 3;
                int c = (s & 7) ^ (r & 7);
                const float* g = enc + (m0 + r) * 1024 + (kt + 1) * 32 + c * 4;
                float* lb = &Abuf[buf ^ 1][(i * 256 + w * 64) * 4];
                __builtin_amdgcn_global_load_lds(
                    (const __attribute__((address_space(1))) void*)g,
                    (__attribute__((address_space(3))) void*)lb, 16, 0, 0);
            }
            // prefetch B frags for kt+1 (L2-hot), consumed only after next barrier
#pragma unroll
            for (int nt = 0; nt < 4; ++nt)
                bfr[p ^ 1][nt] = *(const bf16x8*)(bptr[nt] + (size_t)(kt + 1) * 32);
        }

        // compute tile kt: LDS + regs only, no vmem waits here
        const float* Ab = Abuf[buf];
#pragma unroll
        for (int mt = 0; mt < 4; ++mt) {
            float4 a0 = *(const float4*)(Ab + sA0[mt]);
            float4 a1 = *(const float4*)(Ab + sA1[mt]);
            bf16x8 af = pack8(a0, a1);
#pragma unroll
            for (int nt = 0; nt < 4; ++nt)
                acc[mt][nt] = __builtin_amdgcn_mfma_f32_16x16x32_bf16(
                    af, bfr[p][nt], acc[mt][nt], 0, 0, 0);
        }
        buf ^= 1;
    }

    // epilogue: energy = tanh(acc + hb), partial = sum_d v[d]*energy (this N-slice)
    float partial[4][4];
#pragma unroll
    for (int mt = 0; mt < 4; ++mt)
#pragma unroll
        for (int r = 0; r < 4; ++r) partial[mt][r] = 0.f;

#pragma unroll
    for (int nt = 0; nt < 4; ++nt) {
        int d = n0 + nt * 16 + ln;
        float hbv = hb[bidx * 512 + d];
        float vv  = v[d];
#pragma unroll
        for (int mt = 0; mt < 4; ++mt)
#pragma unroll
            for (int r = 0; r < 4; ++r) {
                float x = acc[mt][nt][r] + hbv;
                float e = __expf(2.f * x);          // tanh(x) = 1 - 2/(e^{2x}+1)
                partial[mt][r] += vv * (1.f - 2.f / (e + 1.f));
            }
    }
#pragma unroll
    for (int mt = 0; mt < 4; ++mt)
#pragma unroll
        for (int r = 0; r < 4; ++r) {
            float s = partial[mt][r];
            s += __shfl_xor(s, 1);
            s += __shfl_xor(s, 2);
            s += __shfl_xor(s, 4);
            s += __shfl_xor(s, 8);
            partial[mt][r] = s;
        }
    if (ln == 0) {
#pragma unroll
        for (int mt = 0; mt < 4; ++mt)
#pragma unroll
            for (int r = 0; r < 4; ++r)
                spart[wn][wm * 64 + mt * 16 + q * 4 + r] = partial[mt][r];
    }
    __syncthreads();
    if (tid < 128)
        atomicAdd(&scores[m0 + tid], spart[0][tid] + spart[1][tid]);
}

// ---- softmax over S=2048 per b ----
__global__ void softmax_kernel(const float* __restrict__ scores, float* __restrict__ out) {
    int b = blockIdx.x;
    const float* sc = scores + b * 2048;
    __shared__ float wred[4], wsum[4];

    float lmax = -1e30f;
    for (int i = threadIdx.x; i < 2048; i += 256) lmax = fmaxf(lmax, sc[i]);
#pragma unroll
    for (int m = 1; m < 64; m <<= 1) lmax = fmaxf(lmax, __shfl_xor(lmax, m));
    if ((threadIdx.x & 63) == 0) wred[threadIdx.x >> 6] = lmax;
    __syncthreads();
    float gmax = fmaxf(fmaxf(wred[0], wred[1]), fmaxf(wred[2], wred[3]));

    float lsum = 0.f;
    for (int i = threadIdx.x; i < 2048; i += 256) lsum += __expf(sc[i] - gmax);
#pragma unroll
    for (int m = 1; m < 64; m <<= 1) lsum += __shfl_xor(lsum, m);
    if ((threadIdx.x & 63) == 0) wsum[threadIdx.x >> 6] = lsum;
    __syncthreads();
    float inv = 1.f / (wsum[0] + wsum[1] + wsum[2] + wsum[3]);

    for (int i = threadIdx.x; i < 2048; i += 256)
        out[b * 2048 + i] = __expf(sc[i] - gmax) * inv;
}

extern "C" void kernel_launch(void* const* d_in, const int* in_sizes, int n_in,
                              void* d_out, int out_size, void* d_ws, size_t ws_size,
                              hipStream_t stream) {
    const float* hidden = (const float*)d_in[0];   // 32 x 512
    const float* enc    = (const float*)d_in[1];   // 32 x 2048 x 1024
    const float* W      = (const float*)d_in[2];   // 512 x 1536
    const float* bias   = (const float*)d_in[3];   // 512
    const float* v      = (const float*)d_in[4];   // 512
    float* out = (float*)d_out;                    // 32 x 1 x 2048

    char* ws = (char*)d_ws;
    ushort* Wbf   = (ushort*)(ws + WS_WBF);
    float*  hb    = (float*)(ws + WS_HB);
    float*  score = (float*)(ws + WS_SCORE);

    hipLaunchKernelGGL(prep_kernel,  dim3(640),  dim3(256), 0, stream,
                       W, hidden, bias, Wbf, hb, score);
    hipLaunchKernelGGL(eproj_scores, dim3(2048), dim3(256), 0, stream,
                       enc, Wbf, hb, v, score);
    hipLaunchKernelGGL(softmax_kernel, dim3(32), dim3(256), 0, stream, score, out);
}

// Round 4
// 488.509 us; speedup vs baseline: 1.2394x; 1.0410x over previous
//
#include <hip/hip_runtime.h>
#include <hip/hip_bf16.h>

// Problem: B=32, S=2048, ENC=1024, DEC=512
//   h_proj[b,e]   = sum_d hidden[b,d] * W[e,d]            (Wh = W[:, :512])
//   e_proj[b,s,d] = sum_e enc[b,s,e] * W[d, 512+e]        (We = W[:, 512:])
//   energy = tanh(e_proj + h_proj + bias); scores = v . energy; attn = softmax_s

typedef __attribute__((ext_vector_type(8))) short bf16x8;
typedef __attribute__((ext_vector_type(4))) float f32x4;

__device__ __forceinline__ ushort f2bf(float x) {
    __hip_bfloat16 h = __float2bfloat16(x);
    return *reinterpret_cast<ushort*>(&h);
}

__device__ __forceinline__ bf16x8 pack8(float4 a, float4 b) {
    bf16x8 o;
    o[0] = (short)f2bf(a.x); o[1] = (short)f2bf(a.y);
    o[2] = (short)f2bf(a.z); o[3] = (short)f2bf(a.w);
    o[4] = (short)f2bf(b.x); o[5] = (short)f2bf(b.y);
    o[6] = (short)f2bf(b.z); o[7] = (short)f2bf(b.w);
    return o;
}

// ws layout (bytes):
//   [0, 1MB)            : Wbf  bf16 [512][1024]  (We: row n=d, col k=e, k-contiguous)
//   [1MB, 1MB+64KB)     : hb   f32  [32][512]    (h_proj + bias)
//   [1MB+64KB, +256KB)  : scores f32 [32][2048]  (zeroed by prep; eproj atomicAdds)
#define WS_WBF   0
#define WS_HB    (1u << 20)
#define WS_SCORE ((1u << 20) + (64u << 10))

// ---- prep: convert We->bf16 (blocks 0..511), hproj (512..575), zero scores (576..639)
__global__ void prep_kernel(const float* __restrict__ W,
                            const float* __restrict__ hidden,
                            const float* __restrict__ bias,
                            ushort* __restrict__ Wbf,
                            float* __restrict__ hb,
                            float* __restrict__ score) {
    const int bid = blockIdx.x, tid = threadIdx.x;
    if (bid < 512) {
        int idx = bid * 256 + tid;
        int d  = idx >> 8;
        int e4 = (idx & 255) * 4;
        float4 f = *(const float4*)(W + (size_t)d * 1536 + 512 + e4);
        ushort4 u;
        u.x = f2bf(f.x); u.y = f2bf(f.y); u.z = f2bf(f.z); u.w = f2bf(f.w);
        *(ushort4*)(Wbf + (size_t)d * 1024 + e4) = u;
    } else if (bid < 576) {
        int idx = (bid - 512) * 256 + tid;        // 0..16383 = 32*512
        int b = idx >> 9, d = idx & 511;
        const float4* hp = (const float4*)(hidden + b * 512);
        const float4* wp = (const float4*)(W + (size_t)d * 1536);
        float acc = 0.f;
#pragma unroll 8
        for (int j = 0; j < 128; ++j) {
            float4 h = hp[j], w = wp[j];
            acc += h.x * w.x + h.y * w.y + h.z * w.z + h.w * w.w;
        }
        hb[idx] = acc + bias[d];
    } else {
        int idx = (bid - 576) * 256 + tid;        // 16384 threads x 4 floats = 65536
        float4 z = {0.f, 0.f, 0.f, 0.f};
        *(float4*)(score + (size_t)idx * 4) = z;
    }
}

// ---- main: e_proj GEMM (M=65536,N=512,K=1024) fused tanh + v-dot -> scores ----
// Grid 2048 = 1024 M-blocks x 2 N-blocks (N fast). Block 256 thr = 4 waves,
// each wave 64x64 (acc 4x4 f32x4 = 64 regs). BM=64, BN=256, BK=32.
// K-loop is grouped: ONE barrier per 4 kt. LDS = 2 half-buffers x 4 stages x
// 8KB = 64KB. At group g's barrier, the half being consumed was async-DMA'd
// (global_load_lds, 16B) a FULL GROUP (~700cy of compute) earlier, so the
// barrier's implicit vmcnt(0) drain finds the loads already landed — this is
// the restructured K-loop the m97 2-barrier shape can't express.
// B frags are register-double-buffered per kt inside the group (no barriers
// between kts, so the compiler's fine-grained vmcnt covers them).
__launch_bounds__(256, 2)
__global__ void eproj_scores(const float* __restrict__ enc,
                             const ushort* __restrict__ Wbf,
                             const float* __restrict__ hb,
                             const float* __restrict__ v,
                             float* __restrict__ scores) {
    __shared__ alignas(16) float Abuf[2][4][2048];   // 64KB total (exactly)

    const int tid  = threadIdx.x;
    const int lane = tid & 63, w = tid >> 6;
    const int q = lane >> 4, ln = lane & 15;
    const int  nblk = blockIdx.x & 1;
    const long m0   = (long)(blockIdx.x >> 1) * 64;
    const int  bidx = (int)(m0 >> 11);        // 32 M-blocks per batch row, no straddle
    const int  n0   = nblk * 256 + w * 64;    // wave's 64-col slice

    f32x4 acc[4][4];
#pragma unroll
    for (int mt = 0; mt < 4; ++mt)
#pragma unroll
        for (int nt = 0; nt < 4; ++nt)
            acc[mt][nt] = (f32x4){0.f, 0.f, 0.f, 0.f};

    // B row pointers (per nt); k advances 32 bf16 per kt
    const ushort* bptr[4];
#pragma unroll
    for (int nt = 0; nt < 4; ++nt)
        bptr[nt] = Wbf + (size_t)(n0 + nt * 16 + ln) * 1024 + q * 8;

    // A-frag swizzled offsets (floats) within a stage, invariant over kt
    int sA0[4], sA1[4];
#pragma unroll
    for (int mt = 0; mt < 4; ++mt) {
        int rA = mt * 16 + ln;
        sA0[mt] = (rA * 8 + ((2 * q)     ^ (rA & 7))) * 4;
        sA1[mt] = (rA * 8 + ((2 * q + 1) ^ (rA & 7))) * 4;
    }

    // async DMA of one 4-stage group (64 rows x 128 k floats) into half h
    auto dma_group = [&](int h, int k0) {
#pragma unroll
        for (int st = 0; st < 4; ++st)
#pragma unroll
            for (int i = 0; i < 2; ++i) {
                int s = i * 256 + tid;          // 16B-slot 0..511 within stage
                int r = s >> 3;
                int c = (s & 7) ^ (r & 7);      // XOR swizzle (read-side matches)
                const float* g = enc + (m0 + r) * 1024 + k0 + st * 32 + c * 4;
                float* lb = &Abuf[h][st][(i * 256 + w * 64) * 4];  // wave-uniform
                __builtin_amdgcn_global_load_lds(
                    (const __attribute__((address_space(1))) void*)g,
                    (__attribute__((address_space(3))) void*)lb, 16, 0, 0);
            }
    };

    dma_group(0, 0);                            // group 0 (kt 0..3) -> half 0
    bf16x8 bfr[2][4];
#pragma unroll
    for (int nt = 0; nt < 4; ++nt)              // B frags for kt=0
        bfr[0][nt] = *(const bf16x8*)(bptr[nt]);

    for (int g = 0; g < 8; ++g) {
        __syncthreads();                        // half g&1 ready (DMA'd 1 group ago)
        if (g < 7) dma_group((g + 1) & 1, (g + 1) * 128);

        const float* H = &Abuf[g & 1][0][0];
#pragma unroll
        for (int j = 0; j < 4; ++j) {
            const int kt = g * 4 + j;
            if (kt < 31) {                      // B prefetch for kt+1 (L2-hot)
#pragma unroll
                for (int nt = 0; nt < 4; ++nt)
                    bfr[(j + 1) & 1][nt] =
                        *(const bf16x8*)(bptr[nt] + (size_t)(kt + 1) * 32);
            }
            const float* Ab = H + j * 2048;
#pragma unroll
            for (int mt = 0; mt < 4; ++mt) {
                float4 a0 = *(const float4*)(Ab + sA0[mt]);
                float4 a1 = *(const float4*)(Ab + sA1[mt]);
                bf16x8 af = pack8(a0, a1);
#pragma unroll
                for (int nt = 0; nt < 4; ++nt)
                    acc[mt][nt] = __builtin_amdgcn_mfma_f32_16x16x32_bf16(
                        af, bfr[j & 1][nt], acc[mt][nt], 0, 0, 0);
            }
        }
    }

    // epilogue: energy = tanh(acc + hb), partial = sum_d v[d]*energy (N-slice)
    float partial[4][4];
#pragma unroll
    for (int mt = 0; mt < 4; ++mt)
#pragma unroll
        for (int r = 0; r < 4; ++r) partial[mt][r] = 0.f;

#pragma unroll
    for (int nt = 0; nt < 4; ++nt) {
        int d = n0 + nt * 16 + ln;
        float hbv = hb[bidx * 512 + d];
        float vv  = v[d];
#pragma unroll
        for (int mt = 0; mt < 4; ++mt)
#pragma unroll
            for (int r = 0; r < 4; ++r) {
                float x = acc[mt][nt][r] + hbv;
                float e = __expf(2.f * x);          // tanh(x) = 1 - 2/(e^{2x}+1)
                partial[mt][r] += vv * (1.f - 2.f / (e + 1.f));
            }
    }
#pragma unroll
    for (int mt = 0; mt < 4; ++mt)
#pragma unroll
        for (int r = 0; r < 4; ++r) {
            float s = partial[mt][r];
            s += __shfl_xor(s, 1);
            s += __shfl_xor(s, 2);
            s += __shfl_xor(s, 4);
            s += __shfl_xor(s, 8);
            partial[mt][r] = s;
        }

    __syncthreads();                     // all LDS reads done; reuse Abuf for spart
    float* spart = (float*)Abuf;         // [4][64]
    if (ln == 0) {
#pragma unroll
        for (int mt = 0; mt < 4; ++mt)
#pragma unroll
            for (int r = 0; r < 4; ++r)
                spart[w * 64 + mt * 16 + q * 4 + r] = partial[mt][r];
    }
    __syncthreads();
    if (tid < 64)
        atomicAdd(&scores[m0 + tid],
                  spart[tid] + spart[64 + tid] + spart[128 + tid] + spart[192 + tid]);
}

// ---- softmax over S=2048 per b ----
__global__ void softmax_kernel(const float* __restrict__ scores, float* __restrict__ out) {
    int b = blockIdx.x;
    const float* sc = scores + b * 2048;
    __shared__ float wred[4], wsum[4];

    float lmax = -1e30f;
    for (int i = threadIdx.x; i < 2048; i += 256) lmax = fmaxf(lmax, sc[i]);
#pragma unroll
    for (int m = 1; m < 64; m <<= 1) lmax = fmaxf(lmax, __shfl_xor(lmax, m));
    if ((threadIdx.x & 63) == 0) wred[threadIdx.x >> 6] = lmax;
    __syncthreads();
    float gmax = fmaxf(fmaxf(wred[0], wred[1]), fmaxf(wred[2], wred[3]));

    float lsum = 0.f;
    for (int i = threadIdx.x; i < 2048; i += 256) lsum += __expf(sc[i] - gmax);
#pragma unroll
    for (int m = 1; m < 64; m <<= 1) lsum += __shfl_xor(lsum, m);
    if ((threadIdx.x & 63) == 0) wsum[threadIdx.x >> 6] = lsum;
    __syncthreads();
    float inv = 1.f / (wsum[0] + wsum[1] + wsum[2] + wsum[3]);

    for (int i = threadIdx.x; i < 2048; i += 256)
        out[b * 2048 + i] = __expf(sc[i] - gmax) * inv;
}

extern "C" void kernel_launch(void* const* d_in, const int* in_sizes, int n_in,
                              void* d_out, int out_size, void* d_ws, size_t ws_size,
                              hipStream_t stream) {
    const float* hidden = (const float*)d_in[0];   // 32 x 512
    const float* enc    = (const float*)d_in[1];   // 32 x 2048 x 1024
    const float* W      = (const float*)d_in[2];   // 512 x 1536
    const float* bias   = (const float*)d_in[3];   // 512
    const float* v      = (const float*)d_in[4];   // 512
    float* out = (float*)d_out;                    // 32 x 1 x 2048

    char* ws = (char*)d_ws;
    ushort* Wbf   = (ushort*)(ws + WS_WBF);
    float*  hb    = (float*)(ws + WS_HB);
    float*  score = (float*)(ws + WS_SCORE);

    hipLaunchKernelGGL(prep_kernel,  dim3(640),  dim3(256), 0, stream,
                       W, hidden, bias, Wbf, hb, score);
    hipLaunchKernelGGL(eproj_scores, dim3(2048), dim3(256), 0, stream,
                       enc, Wbf, hb, v, score);
    hipLaunchKernelGGL(softmax_kernel, dim3(32), dim3(256), 0, stream, score, out);
}